// Round 7
// baseline (3003.524 us; speedup 1.0000x reference)
//
#include <hip/hip_runtime.h>

// Inputs: fp32. Outputs: fp32 (established round 3: PASSED).

constexpr int BB = 4;
constexpr int NN = 4096;
constexpr int M1 = 2048;
constexpr int M2 = 512;

// Exact fp32 squared distance matching numpy's (dx*dx) + (dy*dy), no fma contraction.
__device__ __forceinline__ float d2_exact(float dx, float dy) {
    return __fadd_rn(__fmul_rn(dx, dx), __fmul_rn(dy, dy));
}

// DPP move: old = own value => invalid-source lanes keep themselves (idempotent
// under min/max combines). VALU-speed vs ~30-50cyc ds_permute (measured R3->R4).
template<int CTRL>
__device__ __forceinline__ int dppi(int v) {
    return __builtin_amdgcn_update_dpp(v, v, CTRL, 0xF, 0xF, false);
}
template<int CTRL>
__device__ __forceinline__ float dppf(float v) {
    return __int_as_float(dppi<CTRL>(__float_as_int(v)));
}
// One argmax-combine stage carrying (key_hi, key_lo, x, y).
template<int CTRL>
__device__ __forceinline__ void dppc(unsigned& hi, unsigned& lo, float& x, float& y) {
    unsigned ohi = (unsigned)dppi<CTRL>((int)hi);
    unsigned olo = (unsigned)dppi<CTRL>((int)lo);
    float ox = dppf<CTRL>(x), oy = dppf<CTRL>(y);
    unsigned long long ko = ((unsigned long long)ohi << 32) | (unsigned long long)olo;
    unsigned long long kk = ((unsigned long long)hi  << 32) | (unsigned long long)lo;
    bool t = ko > kk;
    hi = t ? ohi : hi;  lo = t ? olo : lo;
    x  = t ? ox  : x;   y  = t ? oy  : y;
}
__device__ __forceinline__ void ladder(unsigned& hi, unsigned& lo, float& x, float& y) {
    dppc<0x111>(hi, lo, x, y);   // row_shr:1
    dppc<0x112>(hi, lo, x, y);   // row_shr:2
    dppc<0x114>(hi, lo, x, y);   // row_shr:4
    dppc<0x118>(hi, lo, x, y);   // row_shr:8
    dppc<0x142>(hi, lo, x, y);   // row_bcast:15
    dppc<0x143>(hi, lo, x, y);   // row_bcast:31  -> full result in lane 63
}

// ordered-int encode for float atomics (monotone in f)
__device__ __forceinline__ unsigned fenc(float f) {
    unsigned u = __float_as_uint(f);
    return (u & 0x80000000u) ? ~u : (u | 0x80000000u);
}
__device__ __forceinline__ float fdec(unsigned e) {
    unsigned u = (e & 0x80000000u) ? (e & 0x7FFFFFFFu) : ~e;
    return __uint_as_float(u);
}

// ---------------------------------------------------------------------------
// lf = tanh(tanh(x@W1+b1)@W2+b2) -> out (fp32); also
// y1[j,f] = lf_j@c1W[0:64] + zones_j*c1W[64] + pos_j@c1W[65:67] + c1b (fp32 ws)
// ---------------------------------------------------------------------------
__global__ __launch_bounds__(256) void k_lf_y1(
    const float2* __restrict__ x, const float* __restrict__ zones,
    const float* __restrict__ W1, const float* __restrict__ b1,
    const float* __restrict__ W2, const float* __restrict__ b2,
    const float* __restrict__ c1W, const float* __restrict__ c1b,
    float* __restrict__ out_lf, float* __restrict__ y1)
{
    __shared__ float sh[4][64];
    __shared__ float sl[4][64];
    int tid = threadIdx.x;
    int p = tid >> 6, f = tid & 63;
    size_t pt = (size_t)blockIdx.x * 4 + p;
    float2 xv = x[pt];
    float hid = tanhf(xv.x * W1[f] + xv.y * W1[64 + f] + b1[f]);
    sh[p][f] = hid;
    __syncthreads();
    float acc = b2[f];
#pragma unroll
    for (int c = 0; c < 64; ++c) acc += sh[p][c] * W2[c * 64 + f];
    float lf = tanhf(acc);
    sl[p][f] = lf;
    out_lf[pt * 64 + f] = lf;
    __syncthreads();
    float acc2 = c1b[f] + zones[pt] * c1W[64 * 64 + f]
               + xv.x * c1W[65 * 64 + f] + xv.y * c1W[66 * 64 + f];
#pragma unroll
    for (int c = 0; c < 64; ++c) acc2 += sl[p][c] * c1W[c * 64 + f];
    y1[pt * 64 + f] = acc2;
}

// ---------------------------------------------------------------------------
// Spatially-pruned exact FPS. Reference semantics preserved bit-for-bit:
//   md[j] = fmin(md[j], d2_exact(j, c_last)); argmax with FIRST-index
//   tie-break via u64 key = bits(md)<<32 | (0xFFFFFFFF - orig_j).
// Counting-sort into 16x16 cells (permutation only; keys carry orig j so the
// global argmax is unchanged). Groups of 64 sorted points, one per (wave,slot).
// Per-group cached record in LDS + exact bbox prune: lb_d2(bbox,c) computed
// with monotone rn arithmetic, so lb <= d2_exact(j,c) for all j in the group;
// if lb >= ub (= group max md) no md changes and the record stays valid.
// Per iteration: A) prune + re-reduce changed groups only; barrier;
// B) all-wave DPP reduce over 64 records + readlane(63) -> next center;
// barrier. No global memory ops in the loop (centers in LDS, SP reused).
// ---------------------------------------------------------------------------
template<int NP, int M>
__global__ __launch_bounds__(512) void k_fps(const float2* __restrict__ pos,
                                             float* __restrict__ ctr)
{
    constexpr int PPT = NP / 512;            // groups per wave / points per lane
    __shared__ float2 SP[NP];                // sorted points -> reused as cent[M]
    __shared__ unsigned SJ[NP];              // sorted orig index (dead after load)
    __shared__ unsigned hist[256];
    __shared__ unsigned cbase[256];
    __shared__ uint4 rec[64];                // per-group argmax record
    __shared__ float4 gboxs[64];             // per-group bbox (minx,maxx,miny,maxy)
    __shared__ unsigned bbx[4];              // encoded minx,maxx,miny,maxy

    int b = blockIdx.x, tid = threadIdx.x, lane = tid & 63, wv = tid >> 6;
    const float2* p = pos + (size_t)b * NP;
    float2* cent = SP;                       // alias, live after register load

    for (int c = tid; c < 256; c += 512) hist[c] = 0u;
    if (tid < 4) bbx[tid] = (tid & 1) ? 0u : 0xFFFFFFFFu;

    float rx[PPT], ry[PPT];
#pragma unroll
    for (int q = 0; q < PPT; ++q) { float2 v = p[tid + q * 512]; rx[q] = v.x; ry[q] = v.y; }
    float2 c0 = p[0];

    // block bbox (binning only; need not be exact-tight)
    float mnx = rx[0], mxx = rx[0], mny = ry[0], mxy = ry[0];
#pragma unroll
    for (int q = 1; q < PPT; ++q) {
        mnx = fminf(mnx, rx[q]); mxx = fmaxf(mxx, rx[q]);
        mny = fminf(mny, ry[q]); mxy = fmaxf(mxy, ry[q]);
    }
#pragma unroll
    for (int st = 0; st < 6; ++st) {
        const int C[6] = {0x111, 0x112, 0x114, 0x118, 0x142, 0x143};
        // manual unroll through template ctrl values
    }
    mnx = fminf(mnx, dppf<0x111>(mnx)); mnx = fminf(mnx, dppf<0x112>(mnx));
    mnx = fminf(mnx, dppf<0x114>(mnx)); mnx = fminf(mnx, dppf<0x118>(mnx));
    mnx = fminf(mnx, dppf<0x142>(mnx)); mnx = fminf(mnx, dppf<0x143>(mnx));
    mxx = fmaxf(mxx, dppf<0x111>(mxx)); mxx = fmaxf(mxx, dppf<0x112>(mxx));
    mxx = fmaxf(mxx, dppf<0x114>(mxx)); mxx = fmaxf(mxx, dppf<0x118>(mxx));
    mxx = fmaxf(mxx, dppf<0x142>(mxx)); mxx = fmaxf(mxx, dppf<0x143>(mxx));
    mny = fminf(mny, dppf<0x111>(mny)); mny = fminf(mny, dppf<0x112>(mny));
    mny = fminf(mny, dppf<0x114>(mny)); mny = fminf(mny, dppf<0x118>(mny));
    mny = fminf(mny, dppf<0x142>(mny)); mny = fminf(mny, dppf<0x143>(mny));
    mxy = fmaxf(mxy, dppf<0x111>(mxy)); mxy = fmaxf(mxy, dppf<0x112>(mxy));
    mxy = fmaxf(mxy, dppf<0x114>(mxy)); mxy = fmaxf(mxy, dppf<0x118>(mxy));
    mxy = fmaxf(mxy, dppf<0x142>(mxy)); mxy = fmaxf(mxy, dppf<0x143>(mxy));
    __syncthreads();                          // hist/bbx init visible
    if (lane == 63) {
        atomicMin(&bbx[0], fenc(mnx)); atomicMax(&bbx[1], fenc(mxx));
        atomicMin(&bbx[2], fenc(mny)); atomicMax(&bbx[3], fenc(mxy));
    }
    __syncthreads();
    float minx = fdec(bbx[0]), maxx = fdec(bbx[1]);
    float miny = fdec(bbx[2]), maxy = fdec(bbx[3]);
    float sxs = 15.9999f / fmaxf(maxx - minx, 1e-20f);
    float sys = 15.9999f / fmaxf(maxy - miny, 1e-20f);

    int cell[PPT];
#pragma unroll
    for (int q = 0; q < PPT; ++q) {
        int gx = (int)fminf(fmaxf((rx[q] - minx) * sxs, 0.0f), 15.0f);
        int gy = (int)fminf(fmaxf((ry[q] - miny) * sys, 0.0f), 15.0f);
        cell[q] = gx + (gy << 4);
        atomicAdd(&hist[cell[q]], 1u);
    }
    __syncthreads();
    if (tid < 256) cbase[tid] = hist[tid];
    __syncthreads();
    for (int off = 1; off < 256; off <<= 1) {     // inclusive scan
        unsigned v = 0u;
        if (tid < 256 && tid >= off) v = cbase[tid - off];
        __syncthreads();
        if (tid < 256) cbase[tid] += v;
        __syncthreads();
    }
    if (tid < 256) { cbase[tid] -= hist[tid]; hist[tid] = 0u; }  // excl base + cursor
    __syncthreads();
#pragma unroll
    for (int q = 0; q < PPT; ++q) {
        unsigned dst = cbase[cell[q]] + atomicAdd(&hist[cell[q]], 1u);
        SP[dst] = make_float2(rx[q], ry[q]);
        SJ[dst] = (unsigned)(tid + q * 512);
    }
    __syncthreads();

    // register-resident sorted points: slot s of wave wv = group wv*PPT+s
    float px[PPT], py[PPT], md[PPT];
    unsigned lowk[PPT];
#pragma unroll
    for (int s = 0; s < PPT; ++s) {
        int idx = (wv * PPT + s) * 64 + lane;
        float2 v = SP[idx];
        px[s] = v.x; py[s] = v.y;
        lowk[s] = 0xFFFFFFFFu - SJ[idx];
        md[s] = 1e10f;
    }
    // exact per-group bboxes from actual members
#pragma unroll
    for (int s = 0; s < PPT; ++s) {
        float a = px[s], bx_ = px[s], c = py[s], d = py[s];
        a  = fminf(a,  dppf<0x111>(a));  a  = fminf(a,  dppf<0x112>(a));
        a  = fminf(a,  dppf<0x114>(a));  a  = fminf(a,  dppf<0x118>(a));
        a  = fminf(a,  dppf<0x142>(a));  a  = fminf(a,  dppf<0x143>(a));
        bx_ = fmaxf(bx_, dppf<0x111>(bx_)); bx_ = fmaxf(bx_, dppf<0x112>(bx_));
        bx_ = fmaxf(bx_, dppf<0x114>(bx_)); bx_ = fmaxf(bx_, dppf<0x118>(bx_));
        bx_ = fmaxf(bx_, dppf<0x142>(bx_)); bx_ = fmaxf(bx_, dppf<0x143>(bx_));
        c  = fminf(c,  dppf<0x111>(c));  c  = fminf(c,  dppf<0x112>(c));
        c  = fminf(c,  dppf<0x114>(c));  c  = fminf(c,  dppf<0x118>(c));
        c  = fminf(c,  dppf<0x142>(c));  c  = fminf(c,  dppf<0x143>(c));
        d  = fmaxf(d,  dppf<0x111>(d));  d  = fmaxf(d,  dppf<0x112>(d));
        d  = fmaxf(d,  dppf<0x114>(d));  d  = fmaxf(d,  dppf<0x118>(d));
        d  = fmaxf(d,  dppf<0x142>(d));  d  = fmaxf(d,  dppf<0x143>(d));
        if (lane == 63) gboxs[wv * PPT + s] = make_float4(a, bx_, c, d);
    }
    if (tid < 64) rec[tid] = make_uint4(0u, 0u, 0u, 0u);  // losers for lanes >= NG
    if (tid == 0) cent[0] = c0;
    __syncthreads();
    float4 gb = gboxs[wv * PPT + (lane < PPT ? lane : 0)];  // per-lane cached bbox
    float ub = 1e10f;                                       // per-lane cached group max-md

    float cx = c0.x, cy = c0.y;
    for (int it = 1; it < M; ++it) {
        // ---- A: prune + update own groups (no cross-wave LDS reads) ----
        bool chg = false;
        if (lane < PPT) {
            float lbx = fmaxf(fmaxf(__fsub_rn(gb.x, cx), __fsub_rn(cx, gb.y)), 0.0f);
            float lby = fmaxf(fmaxf(__fsub_rn(gb.z, cy), __fsub_rn(cy, gb.w)), 0.0f);
            float lb = __fadd_rn(__fmul_rn(lbx, lbx), __fmul_rn(lby, lby));
            chg = lb < ub;
        }
        unsigned long long mask = __ballot(chg);
#pragma unroll
        for (int s = 0; s < PPT; ++s) {
            if (mask & (1ull << s)) {          // wave-uniform branch
                float m = fminf(md[s], d2_exact(px[s] - cx, py[s] - cy));
                md[s] = m;
                unsigned hi = __float_as_uint(m), lo = lowk[s];
                float bx2 = px[s], by2 = py[s];
                ladder(hi, lo, bx2, by2);
                if (lane == 63)
                    rec[wv * PPT + s] = make_uint4(hi, lo, __float_as_uint(bx2),
                                                   __float_as_uint(by2));
                unsigned nub = (unsigned)__builtin_amdgcn_readlane((int)hi, 63);
                ub = (lane == s) ? __uint_as_float(nub) : ub;
            }
        }
        __syncthreads();
        // ---- B: all-wave reduce over 64 records ----
        uint4 r = rec[lane];
        unsigned hi = r.x, lo = r.y;
        float bx2 = __uint_as_float(r.z), by2 = __uint_as_float(r.w);
        ladder(hi, lo, bx2, by2);
        cx = __int_as_float(__builtin_amdgcn_readlane(__float_as_int(bx2), 63));
        cy = __int_as_float(__builtin_amdgcn_readlane(__float_as_int(by2), 63));
        if (tid == 0) cent[it] = make_float2(cx, cy);
        __syncthreads();                       // protects rec reads vs next A
    }
    float2* co = (float2*)(ctr + (size_t)b * M * 2);
    for (int i = tid; i < M; i += 512) co[i] = cent[i];
}

// ---------------------------------------------------------------------------
// Set abstraction: h[i,f] = max_{j: d2(j,i)<=r2} y[j,f]  -  ctr_i @ W_rel.
// ---------------------------------------------------------------------------
__global__ __launch_bounds__(256) void k_sa(
    const float2* __restrict__ candpos, const float* __restrict__ y,
    const float* __restrict__ ctr, const float* __restrict__ W,
    int NP, int F, int relrow, float r2, float* __restrict__ hout)
{
    __shared__ int cnt;
    __shared__ int list[4096];
    int tid = threadIdx.x;
    int b = blockIdx.y;
    size_t crow = (size_t)b * gridDim.x + blockIdx.x;
    if (tid == 0) cnt = 0;
    __syncthreads();
    float cx = ctr[crow * 2], cy = ctr[crow * 2 + 1];
    const float2* cp = candpos + (size_t)b * NP;
    for (int j = tid; j < NP; j += 256) {
        float2 pj = cp[j];
        float d2 = d2_exact(pj.x - cx, pj.y - cy);
        if (d2 <= r2) { int t = atomicAdd(&cnt, 1); list[t] = j; }
    }
    __syncthreads();
    int n = cnt;
    for (int f = tid; f < F; f += 256) {
        float m = -3.0e38f;
        for (int t = 0; t < n; ++t)
            m = fmaxf(m, y[((size_t)b * NP + list[t]) * F + f]);
        float ct = cx * W[(size_t)relrow * F + f] + cy * W[(size_t)(relrow + 1) * F + f];
        hout[crow * F + f] = m - ct;
    }
}

// ---------------------------------------------------------------------------
// y2[j,f] = h1_j @ c2W[0:64] + pos_j @ c2W[64:66] + c2b
// ---------------------------------------------------------------------------
__global__ __launch_bounds__(128) void k_y2(
    const float* __restrict__ h1, const float* __restrict__ p1,
    const float* __restrict__ W, const float* __restrict__ bb,
    float* __restrict__ y2)
{
    __shared__ float sh[64];
    size_t row = blockIdx.x;
    int f = threadIdx.x;
    if (f < 64) sh[f] = h1[row * 64 + f];
    __syncthreads();
    float acc = bb[f] + p1[row * 2] * W[64 * 128 + f]
              + p1[row * 2 + 1] * W[65 * 128 + f];
#pragma unroll
    for (int c = 0; c < 64; ++c) acc += sh[c] * W[c * 128 + f];
    y2[row * 128 + f] = acc;
}

// ---------------------------------------------------------------------------
// g[i,f] = [h2_i, pos_i] @ c3W + c3b; partial max over 8 rows/thread.
// ---------------------------------------------------------------------------
__global__ __launch_bounds__(256) void k_g(
    const float* __restrict__ h2, const float* __restrict__ p2,
    const float* __restrict__ W3, const float* __restrict__ b3,
    float* __restrict__ part)
{
    int f = blockIdx.x * 256 + threadIdx.x;
    int b = blockIdx.z;
    int i0 = blockIdx.y * 8;
    float acc[8];
    float bbv = b3[f];
#pragma unroll
    for (int ii = 0; ii < 8; ++ii) acc[ii] = bbv;
    const float* hrow = h2 + ((size_t)b * M2 + i0) * 128;
    for (int c = 0; c < 128; ++c) {
        float w = W3[(size_t)c * 1024 + f];
#pragma unroll
        for (int ii = 0; ii < 8; ++ii) acc[ii] += hrow[ii * 128 + c] * w;
    }
    float wx = W3[(size_t)128 * 1024 + f];
    float wy = W3[(size_t)129 * 1024 + f];
    const float* prow = p2 + ((size_t)b * M2 + i0) * 2;
    float m = -3.0e38f;
#pragma unroll
    for (int ii = 0; ii < 8; ++ii) {
        float g = acc[ii] + prow[ii * 2] * wx + prow[ii * 2 + 1] * wy;
        m = fmaxf(m, g);
    }
    part[((size_t)b * 64 + blockIdx.y) * 1024 + f] = m;
}

__global__ __launch_bounds__(256) void k_gmax(const float* __restrict__ part,
                                              float* __restrict__ outg)
{
    int f = blockIdx.x * 256 + threadIdx.x;   // 0..4095
    int b = f >> 10, fl = f & 1023;
    float m = -3.0e38f;
#pragma unroll 8
    for (int ig = 0; ig < 64; ++ig)
        m = fmaxf(m, part[((size_t)b * 64 + ig) * 1024 + fl]);
    outg[f] = m;
}

extern "C" void kernel_launch(void* const* d_in, const int* in_sizes, int n_in,
                              void* d_out, int out_size, void* d_ws, size_t ws_size,
                              hipStream_t stream)
{
    const float* x    = (const float*)d_in[0];
    const float* zon  = (const float*)d_in[1];
    const float* lfW1 = (const float*)d_in[2];
    const float* lfb1 = (const float*)d_in[3];
    const float* lfW2 = (const float*)d_in[4];
    const float* lfb2 = (const float*)d_in[5];
    const float* c1W  = (const float*)d_in[6];
    const float* c1b  = (const float*)d_in[7];
    const float* c2W  = (const float*)d_in[8];
    const float* c2b  = (const float*)d_in[9];
    const float* c3W  = (const float*)d_in[10];
    const float* c3b  = (const float*)d_in[11];
    float* out = (float*)d_out;

    // Workspace (fp32). "big" (4 MB) reused: y1 -> y2 -> part.
    char* w = (char*)d_ws;
    float* big = (float*)w;                    w += (size_t)BB * NN * 64 * 4;   // 4 MB
    float* p1  = (float*)w;                    w += (size_t)BB * M1 * 2 * 4;
    float* h1  = (float*)w;                    w += (size_t)BB * M1 * 64 * 4;   // 2 MB
    float* p2  = (float*)w;                    w += (size_t)BB * M2 * 2 * 4;
    float* h2  = (float*)w;                    w += (size_t)BB * M2 * 128 * 4;  // 1 MB
    float* y1 = big, * y2 = big, * part = big;

    k_lf_y1<<<BB * NN / 4, 256, 0, stream>>>((const float2*)x, zon, lfW1, lfb1,
                                             lfW2, lfb2, c1W, c1b, out, y1);
    k_fps<NN, M1><<<BB, 512, 0, stream>>>((const float2*)x, p1);
    k_sa<<<dim3(M1, BB), 256, 0, stream>>>((const float2*)x, y1, p1, c1W,
                                           NN, 64, 65, 0.25f, h1);
    k_fps<M1, M2><<<BB, 512, 0, stream>>>((const float2*)p1, p2);
    k_y2<<<BB * M1, 128, 0, stream>>>(h1, p1, c2W, c2b, y2);
    k_sa<<<dim3(M2, BB), 256, 0, stream>>>((const float2*)p1, y2, p2, c2W,
                                           M1, 128, 64, 1.0f, h2);
    k_g<<<dim3(4, 64, BB), 256, 0, stream>>>(h2, p2, c3W, c3b, part);
    k_gmax<<<16, 256, 0, stream>>>(part, out + (size_t)BB * NN * 64);
}

// Round 8
// 2002.573 us; speedup vs baseline: 1.4998x; 1.4998x over previous
//
#include <hip/hip_runtime.h>

// Inputs: fp32. Outputs: fp32 (established round 3: PASSED).

constexpr int BB = 4;
constexpr int NN = 4096;
constexpr int M1 = 2048;
constexpr int M2 = 512;

// Exact fp32 squared distance matching numpy's (dx*dx) + (dy*dy), no fma contraction.
__device__ __forceinline__ float d2_exact(float dx, float dy) {
    return __fadd_rn(__fmul_rn(dx, dx), __fmul_rn(dy, dy));
}

// DPP move (old = own value => invalid-source lanes keep themselves; idempotent
// under max). VALU-speed vs ~30-50 cyc ds_permute shuffles (measured R3->R4).
template<int CTRL>
__device__ __forceinline__ unsigned dppu(unsigned v) {
    return (unsigned)__builtin_amdgcn_update_dpp((int)v, (int)v, CTRL, 0xF, 0xF, false);
}
// Full-wave u32 max -> valid in lane 63 (canonical GCN ladder, validated R5/R6).
__device__ __forceinline__ unsigned wave_umax(unsigned v) {
    unsigned o;
    o = dppu<0x111>(v); v = o > v ? o : v;   // row_shr:1
    o = dppu<0x112>(v); v = o > v ? o : v;   // row_shr:2
    o = dppu<0x114>(v); v = o > v ? o : v;   // row_shr:4
    o = dppu<0x118>(v); v = o > v ? o : v;   // row_shr:8
    o = dppu<0x142>(v); v = o > v ? o : v;   // row_bcast:15
    o = dppu<0x143>(v); v = o > v ? o : v;   // row_bcast:31
    return v;
}

// ---------------------------------------------------------------------------
// lf = tanh(tanh(x@W1+b1)@W2+b2) -> out (fp32); also
// y1[j,f] = lf_j@c1W[0:64] + zones_j*c1W[64] + pos_j@c1W[65:67] + c1b (fp32 ws)
// ---------------------------------------------------------------------------
__global__ __launch_bounds__(256) void k_lf_y1(
    const float2* __restrict__ x, const float* __restrict__ zones,
    const float* __restrict__ W1, const float* __restrict__ b1,
    const float* __restrict__ W2, const float* __restrict__ b2,
    const float* __restrict__ c1W, const float* __restrict__ c1b,
    float* __restrict__ out_lf, float* __restrict__ y1)
{
    __shared__ float sh[4][64];
    __shared__ float sl[4][64];
    int tid = threadIdx.x;
    int p = tid >> 6, f = tid & 63;
    size_t pt = (size_t)blockIdx.x * 4 + p;
    float2 xv = x[pt];
    float hid = tanhf(xv.x * W1[f] + xv.y * W1[64 + f] + b1[f]);
    sh[p][f] = hid;
    __syncthreads();
    float acc = b2[f];
#pragma unroll
    for (int c = 0; c < 64; ++c) acc += sh[p][c] * W2[c * 64 + f];
    float lf = tanhf(acc);
    sl[p][f] = lf;
    out_lf[pt * 64 + f] = lf;
    __syncthreads();
    float acc2 = c1b[f] + zones[pt] * c1W[64 * 64 + f]
               + xv.x * c1W[65 * 64 + f] + xv.y * c1W[66 * 64 + f];
#pragma unroll
    for (int c = 0; c < 64; ++c) acc2 += sl[p][c] * c1W[c * 64 + f];
    y1[pt * 64 + f] = acc2;
}

// ---------------------------------------------------------------------------
// Farthest point sampling — value-only two-phase reduction, bit-exact vs ref:
//   md[j] = fmin(md[j], d2_exact(j, c_last));
//   argmax with FIRST-index tie-break: phase A finds max md (as u32 bits —
//   md>=0 so bit order == value order); phase B finds max (0xFFFFFFFF - j)
//   among slots with bits(md) == max (exact equality <=> value equality).
// No 64-bit keys, no payload ladders (the R6 cost): winner position comes
// from a broadcast LDS read of PTS[j]. Cross-wave combine via ds_max_u32
// into parity-double-buffered slots (reset by tid0 in the B-window — last
// readers of the other parity are separated by >=1 barrier). 2 barriers/iter.
// No global memory ops inside the loop.
// ---------------------------------------------------------------------------
template<int NP, int M>
__global__ __launch_bounds__(512) void k_fps(const float2* __restrict__ pos,
                                             float* __restrict__ ctr)
{
    constexpr int PPT = NP / 512;
    __shared__ float2 PTS[NP];           // original-order points (broadcast src)
    __shared__ float2 cent[M];           // selected centers (copied out at end)
    __shared__ unsigned valslot[2];
    __shared__ unsigned lkslot[2];
    int b = blockIdx.x, tid = threadIdx.x, lane = tid & 63;
    const float2* p = pos + (size_t)b * NP;

    float px[PPT], py[PPT], md[PPT];
#pragma unroll
    for (int q = 0; q < PPT; ++q) {
        float2 v = p[tid + q * 512];
        px[q] = v.x; py[q] = v.y; md[q] = 1e10f;
        PTS[tid + q * 512] = v;
    }
    if (tid < 2) { valslot[tid] = 0u; lkslot[tid] = 0u; }
    float2 c0 = p[0];
    float cx = c0.x, cy = c0.y;
    if (tid == 0) cent[0] = c0;
    __syncthreads();

    for (int it = 1; it < M; ++it) {
        int par = it & 1;
        // ---- A: min-update + per-lane value max (bits; md>=0 so monotone) ----
        unsigned bmu = 0u;
#pragma unroll
        for (int q = 0; q < PPT; ++q) {
            float m = fminf(md[q], d2_exact(px[q] - cx, py[q] - cy));
            md[q] = m;
            unsigned mb = __float_as_uint(m);
            bmu = mb > bmu ? mb : bmu;
        }
        bmu = wave_umax(bmu);
        if (lane == 63) atomicMax(&valslot[par], bmu);
        __syncthreads();                                   // b1
        unsigned bmv = valslot[par];
        // ---- B: first-index tie-break (max of ~j among exact matches) ----
        unsigned lk = 0u;
#pragma unroll
        for (int q = 0; q < PPT; ++q) {
            unsigned cand = (__float_as_uint(md[q]) == bmv)
                          ? (0xFFFFFFFFu - (unsigned)(tid + q * 512)) : 0u;
            lk = cand > lk ? cand : lk;
        }
        lk = wave_umax(lk);
        if (lane == 63) atomicMax(&lkslot[par], lk);
        if (tid == 0) { valslot[1 - par] = 0u; lkslot[1 - par] = 0u; }
        __syncthreads();                                   // b2
        // ---- C: dereference winner position (broadcast LDS read) ----
        unsigned wlk = lkslot[par];
        int j = (int)(0xFFFFFFFFu - wlk);
        float2 c = PTS[j];
        cx = c.x; cy = c.y;
        if (tid == 0) cent[it] = c;
    }
    __syncthreads();
    float2* co = (float2*)(ctr + (size_t)b * M * 2);
    for (int i = tid; i < M; i += 512) co[i] = cent[i];
}

// ---------------------------------------------------------------------------
// Set abstraction: h[i,f] = max_{j: d2(j,i)<=r2} y[j,f]  -  ctr_i @ W_rel.
// ---------------------------------------------------------------------------
__global__ __launch_bounds__(256) void k_sa(
    const float2* __restrict__ candpos, const float* __restrict__ y,
    const float* __restrict__ ctr, const float* __restrict__ W,
    int NP, int F, int relrow, float r2, float* __restrict__ hout)
{
    __shared__ int cnt;
    __shared__ int list[4096];
    int tid = threadIdx.x;
    int b = blockIdx.y;
    size_t crow = (size_t)b * gridDim.x + blockIdx.x;
    if (tid == 0) cnt = 0;
    __syncthreads();
    float cx = ctr[crow * 2], cy = ctr[crow * 2 + 1];
    const float2* cp = candpos + (size_t)b * NP;
    for (int j = tid; j < NP; j += 256) {
        float2 pj = cp[j];
        float d2 = d2_exact(pj.x - cx, pj.y - cy);
        if (d2 <= r2) { int t = atomicAdd(&cnt, 1); list[t] = j; }
    }
    __syncthreads();
    int n = cnt;
    for (int f = tid; f < F; f += 256) {
        float m = -3.0e38f;
        for (int t = 0; t < n; ++t)
            m = fmaxf(m, y[((size_t)b * NP + list[t]) * F + f]);
        float ct = cx * W[(size_t)relrow * F + f] + cy * W[(size_t)(relrow + 1) * F + f];
        hout[crow * F + f] = m - ct;
    }
}

// ---------------------------------------------------------------------------
// y2[j,f] = h1_j @ c2W[0:64] + pos_j @ c2W[64:66] + c2b
// ---------------------------------------------------------------------------
__global__ __launch_bounds__(128) void k_y2(
    const float* __restrict__ h1, const float* __restrict__ p1,
    const float* __restrict__ W, const float* __restrict__ bb,
    float* __restrict__ y2)
{
    __shared__ float sh[64];
    size_t row = blockIdx.x;
    int f = threadIdx.x;
    if (f < 64) sh[f] = h1[row * 64 + f];
    __syncthreads();
    float acc = bb[f] + p1[row * 2] * W[64 * 128 + f]
              + p1[row * 2 + 1] * W[65 * 128 + f];
#pragma unroll
    for (int c = 0; c < 64; ++c) acc += sh[c] * W[c * 128 + f];
    y2[row * 128 + f] = acc;
}

// ---------------------------------------------------------------------------
// g[i,f] = [h2_i, pos_i] @ c3W + c3b; partial max over 8 rows/thread.
// ---------------------------------------------------------------------------
__global__ __launch_bounds__(256) void k_g(
    const float* __restrict__ h2, const float* __restrict__ p2,
    const float* __restrict__ W3, const float* __restrict__ b3,
    float* __restrict__ part)
{
    int f = blockIdx.x * 256 + threadIdx.x;
    int b = blockIdx.z;
    int i0 = blockIdx.y * 8;
    float acc[8];
    float bbv = b3[f];
#pragma unroll
    for (int ii = 0; ii < 8; ++ii) acc[ii] = bbv;
    const float* hrow = h2 + ((size_t)b * M2 + i0) * 128;
    for (int c = 0; c < 128; ++c) {
        float w = W3[(size_t)c * 1024 + f];
#pragma unroll
        for (int ii = 0; ii < 8; ++ii) acc[ii] += hrow[ii * 128 + c] * w;
    }
    float wx = W3[(size_t)128 * 1024 + f];
    float wy = W3[(size_t)129 * 1024 + f];
    const float* prow = p2 + ((size_t)b * M2 + i0) * 2;
    float m = -3.0e38f;
#pragma unroll
    for (int ii = 0; ii < 8; ++ii) {
        float g = acc[ii] + prow[ii * 2] * wx + prow[ii * 2 + 1] * wy;
        m = fmaxf(m, g);
    }
    part[((size_t)b * 64 + blockIdx.y) * 1024 + f] = m;
}

__global__ __launch_bounds__(256) void k_gmax(const float* __restrict__ part,
                                              float* __restrict__ outg)
{
    int f = blockIdx.x * 256 + threadIdx.x;   // 0..4095
    int b = f >> 10, fl = f & 1023;
    float m = -3.0e38f;
#pragma unroll 8
    for (int ig = 0; ig < 64; ++ig)
        m = fmaxf(m, part[((size_t)b * 64 + ig) * 1024 + fl]);
    outg[f] = m;
}

extern "C" void kernel_launch(void* const* d_in, const int* in_sizes, int n_in,
                              void* d_out, int out_size, void* d_ws, size_t ws_size,
                              hipStream_t stream)
{
    const float* x    = (const float*)d_in[0];
    const float* zon  = (const float*)d_in[1];
    const float* lfW1 = (const float*)d_in[2];
    const float* lfb1 = (const float*)d_in[3];
    const float* lfW2 = (const float*)d_in[4];
    const float* lfb2 = (const float*)d_in[5];
    const float* c1W  = (const float*)d_in[6];
    const float* c1b  = (const float*)d_in[7];
    const float* c2W  = (const float*)d_in[8];
    const float* c2b  = (const float*)d_in[9];
    const float* c3W  = (const float*)d_in[10];
    const float* c3b  = (const float*)d_in[11];
    float* out = (float*)d_out;

    // Workspace (fp32). "big" (4 MB) reused: y1 -> y2 -> part.
    char* w = (char*)d_ws;
    float* big = (float*)w;                    w += (size_t)BB * NN * 64 * 4;   // 4 MB
    float* p1  = (float*)w;                    w += (size_t)BB * M1 * 2 * 4;
    float* h1  = (float*)w;                    w += (size_t)BB * M1 * 64 * 4;   // 2 MB
    float* p2  = (float*)w;                    w += (size_t)BB * M2 * 2 * 4;
    float* h2  = (float*)w;                    w += (size_t)BB * M2 * 128 * 4;  // 1 MB
    float* y1 = big, * y2 = big, * part = big;

    k_lf_y1<<<BB * NN / 4, 256, 0, stream>>>((const float2*)x, zon, lfW1, lfb1,
                                             lfW2, lfb2, c1W, c1b, out, y1);
    k_fps<NN, M1><<<BB, 512, 0, stream>>>((const float2*)x, p1);
    k_sa<<<dim3(M1, BB), 256, 0, stream>>>((const float2*)x, y1, p1, c1W,
                                           NN, 64, 65, 0.25f, h1);
    k_fps<M1, M2><<<BB, 512, 0, stream>>>((const float2*)p1, p2);
    k_y2<<<BB * M1, 128, 0, stream>>>(h1, p1, c2W, c2b, y2);
    k_sa<<<dim3(M2, BB), 256, 0, stream>>>((const float2*)p1, y2, p2, c2W,
                                           M1, 128, 64, 1.0f, h2);
    k_g<<<dim3(4, 64, BB), 256, 0, stream>>>(h2, p2, c3W, c3b, part);
    k_gmax<<<16, 256, 0, stream>>>(part, out + (size_t)BB * NN * 64);
}